// Round 9
// baseline (32.415 us; speedup 1.0000x reference)
//
#include <hip/hip_runtime.h>
#include <hip/hip_bf16.h>

// FSMN: strided dilated depthwise conv over time + residual.
// R7 finding: flat register window failed because hipcc SANK the 39 loads to
// their uses (VGPR 60 -> serialized dep chains). R8 LDS staging: 27.8us,
// barrier-drain + LDS capacity cap occupancy.
// R9 fix: R7 structure + __builtin_amdgcn_sched_barrier(0) fence between the
// window-load block and compute — hard stop against load sinking. Interior
// strips (197/200) take a branch-free single-BB path: 39 unconditional f32x2
// loads back-to-back -> ~19.5KB in flight/wave; edge strips keep guards.

typedef float f32x2 __attribute__((ext_vector_type(2)));

constexpr int B = 16;
constexpr int T = 2000;
constexpr int D = 512;
constexpr int D2 = D / 2;          // 256 f32x2 per (b,t) row
constexpr int NTAP = 16;           // filt rows: 0..9 left, 10 center, 11..15 right
constexpr int S = 10;              // outputs per thread strip
constexpr int NSTRIP = T / S;      // 200
constexpr int ITERS = S / 2;       // 5 double-steps
constexpr int WSPAN = 39;          // slots [t0-20 .. t0+18]
constexpr int NXCD = 8;

__global__ __launch_bounds__(256, 4) void fsmn_f2_kernel(
    const f32x2* __restrict__ x,      // (B,T,D2)
    const f32x2* __restrict__ filt,   // (16,D2)
    f32x2* __restrict__ out)          // (B,T,D2)
{
    // grid = B*NSTRIP = 3200 blocks; bid -> (b, strip), strip fastest so
    // adjacent strips (sharing halo rows) land on the same XCD chunk.
    const int nbl = B * NSTRIP;              // 3200
    const int cpx = nbl / NXCD;              // 400
    int bid = blockIdx.x;
    bid = (bid & (NXCD - 1)) * cpx + (bid >> 3);   // chunked XCD swizzle

    const int strip = bid % NSTRIP;
    const int b     = bid / NSTRIP;
    const int d2    = (int)threadIdx.x;      // f32x2 column, 0..255
    const int t0    = strip * S;

    const f32x2* xp = x + (size_t)(b * T) * D2 + d2;   // xp[p*D2] = x[b,p,:]

    // filter taps for this d-pair (independent loads, overlap with window)
    f32x2 F[NTAP];
#pragma unroll
    for (int k = 0; k < NTAP; ++k) F[k] = filt[k * D2 + d2];
    F[10].x += 1.0f;
    F[10].y += 1.0f;

    // flat window: W[m] = x[b, t0-20+m, :], zero outside [0,T)
    f32x2 W[WSPAN];
    if (t0 >= 20 && t0 + 18 < T) {
        // interior strip: single BB, 39 unconditional back-to-back loads
#pragma unroll
        for (int m = 0; m < WSPAN; ++m) W[m] = xp[(t0 - 20 + m) * D2];
    } else {
        // edge strip (block-uniform scalar guards)
#pragma unroll
        for (int m = 0; m < WSPAN; ++m) {
            const int p = t0 - 20 + m;
            W[m] = (p >= 0 && p < T) ? xp[p * D2] : (f32x2)(0.0f);
        }
    }

    // Hard scheduling fence: nothing moves across. Forces all window loads
    // to be issued before any FMA consumes them (keeps W live -> MLP).
    __builtin_amdgcn_sched_barrier(0);

    f32x2* op = out + (size_t)(b * T + t0) * D2 + d2;

#pragma unroll
    for (int i = 0; i < ITERS; ++i) {
        const int s0 = 2 * i;   // slot of (t-20) for even output t = t0+2i
        f32x2 a0, a1;
        a0.x = W[s0].x * F[0].x;         a0.y = W[s0].y * F[0].y;
        a1.x = W[s0 + 1].x * F[0].x;     a1.y = W[s0 + 1].y * F[0].y;

        // left taps k=1..9 (slot s0+2k) and center k=10 (slot s0+20, +1 folded)
#pragma unroll
        for (int k = 1; k <= 10; ++k) {
            a0.x = fmaf(W[s0 + 2 * k].x,     F[k].x, a0.x);
            a0.y = fmaf(W[s0 + 2 * k].y,     F[k].y, a0.y);
            a1.x = fmaf(W[s0 + 2 * k + 1].x, F[k].x, a1.x);
            a1.y = fmaf(W[s0 + 2 * k + 1].y, F[k].y, a1.y);
        }
        // right taps k=0..4 -> filt[11+k], slot s0+21+2k
#pragma unroll
        for (int k = 0; k <= 4; ++k) {
            a0.x = fmaf(W[s0 + 21 + 2 * k].x, F[11 + k].x, a0.x);
            a0.y = fmaf(W[s0 + 21 + 2 * k].y, F[11 + k].y, a0.y);
            a1.x = fmaf(W[s0 + 22 + 2 * k].x, F[11 + k].x, a1.x);
            a1.y = fmaf(W[s0 + 22 + 2 * k].y, F[11 + k].y, a1.y);
        }

        // nontemporal: output is never re-read — keep L2/L3 for input reuse
        __builtin_nontemporal_store(a0, &op[(2 * i) * D2]);
        __builtin_nontemporal_store(a1, &op[(2 * i + 1) * D2]);
    }
}

extern "C" void kernel_launch(void* const* d_in, const int* in_sizes, int n_in,
                              void* d_out, int out_size, void* d_ws, size_t ws_size,
                              hipStream_t stream) {
    const f32x2* x    = (const f32x2*)d_in[0];
    const f32x2* filt = (const f32x2*)d_in[1];
    f32x2* out        = (f32x2*)d_out;

    const int grid = B * NSTRIP;   // 3200 blocks, /8 XCDs evenly
    fsmn_f2_kernel<<<grid, 256, 0, stream>>>(x, filt, out);
}

// Round 10
// 25.894 us; speedup vs baseline: 1.2518x; 1.2518x over previous
//
#include <hip/hip_runtime.h>
#include <hip/hip_bf16.h>

// FSMN: strided dilated depthwise conv over time + residual.
// R9 finding: sched_barrier(0) cannot stop regalloc from sinking a 39-deep
// register window (VGPR stayed 60) — abandoning flat windows. R5 ring
// (25.5us) is the best structure; its counters (occ 50%, VALU 23%) suggest
// average wave residency, not per-wave MLP, is the remaining limiter.
// R10: identical ring kernel, 512-thread blocks covering full D -> grid
// 3200->1600 blocks of 8 waves. Tests the block-supply/ramp hypothesis.

constexpr int B = 16;
constexpr int T = 2000;
constexpr int D = 512;
constexpr int NTAP = 16;          // filt rows: 0..9 left, 10 center, 11..15 right
constexpr int S = 20;             // outputs per thread strip
constexpr int NSTRIP = T / S;     // 100
constexpr int ITERS = S / 2;      // 10 double-steps
constexpr int NXCD = 8;
constexpr int P = 4;              // prefetch depth in double-steps
constexpr int RING = 32 + 2 * (P - 1);   // 38 live positions: [t-20, t+17]

__global__ __launch_bounds__(512) void fsmn_sw_kernel(
    const float* __restrict__ x,      // (B,T,D)
    const float* __restrict__ filt,   // (16,D)
    float* __restrict__ out)          // (B,T,D)
{
    // grid = B*NSTRIP = 1600 blocks; bid -> (b, strip), strip fastest so
    // adjacent strips (sharing halo rows) land on the same XCD chunk.
    const int nbl = B * NSTRIP;              // 1600
    const int cpx = nbl / NXCD;              // 200
    int bid = blockIdx.x;
    bid = (bid & (NXCD - 1)) * cpx + (bid >> 3);   // chunked XCD swizzle

    const int strip = bid % NSTRIP;
    const int b     = bid / NSTRIP;
    const int d     = (int)threadIdx.x;      // 0..511, full D row
    const int t0    = strip * S;

    const float* xp = x + (size_t)(b * T) * D + d;        // xp[p*D] = x[b,p,d]
    float*       op = out + (size_t)(b * T + t0) * D + d; // op[i*D] = out[b,t0+i,d]

    // filter taps for this d, residual folded into center tap
    float F[NTAP];
#pragma unroll
    for (int k = 0; k < NTAP; ++k) F[k] = filt[k * D + d];
    F[10] += 1.0f;

    // ring window: W[(p - (t0-20)) % RING] holds x[b, p, d]
    // initial fill covers [t0-20, t0+17]; p <= t0+17 <= 1997 < T always.
    float W[RING];
#pragma unroll
    for (int m = 0; m < RING; ++m) {
        const int p = t0 - 20 + m;
        W[m] = (p >= 0) ? xp[p * D] : 0.0f;
    }

#pragma unroll
    for (int i = 0; i < ITERS; ++i) {
        const int base = (2 * i) % RING;      // slot of (t-20), t = t0+2i
        // tap k=0 consumed FIRST: slots base, base+1 hold the oldest rows and
        // are immediately reused by the prefetch writes below.
        float a0 = W[base] * F[0];
        float a1 = W[(base + 1) % RING] * F[0];

        // prefetch the pair first consumed ~P iterations ahead
        if (i + P < ITERS) {
            const int p0 = t0 + 18 + 2 * i;
            const int p1 = p0 + 1;
            W[base]              = (p0 < T) ? xp[p0 * D] : 0.0f;
            W[(base + 1) % RING] = (p1 < T) ? xp[p1 * D] : 0.0f;
        }

        // even-offset taps k=1..10 (rel = 2k-20); center k=10 has +1 folded
#pragma unroll
        for (int k = 1; k <= 10; ++k) {
            a0 = fmaf(W[(base + 2 * k) % RING],     F[k], a0);
            a1 = fmaf(W[(base + 1 + 2 * k) % RING], F[k], a1);
        }
        // odd-offset taps k=11..15 (rel = 2k-21)
#pragma unroll
        for (int k = 11; k <= 15; ++k) {
            a0 = fmaf(W[(base + 2 * k - 1) % RING], F[k], a0);
            a1 = fmaf(W[(base + 2 * k) % RING],     F[k], a1);
        }

        // nontemporal: output is never re-read — keep L2/L3 for input reuse
        __builtin_nontemporal_store(a0, &op[(2 * i) * D]);
        __builtin_nontemporal_store(a1, &op[(2 * i + 1) * D]);
    }
}

extern "C" void kernel_launch(void* const* d_in, const int* in_sizes, int n_in,
                              void* d_out, int out_size, void* d_ws, size_t ws_size,
                              hipStream_t stream) {
    const float* x    = (const float*)d_in[0];
    const float* filt = (const float*)d_in[1];
    float* out        = (float*)d_out;

    const int grid = B * NSTRIP;   // 1600 blocks of 512 threads, /8 XCDs evenly
    fsmn_sw_kernel<<<grid, 512, 0, stream>>>(x, filt, out);
}